// Round 18
// baseline (150.695 us; speedup 1.0000x reference)
//
#include <hip/hip_runtime.h>

// SelfAttention: x[8,256,64,64] fp32, W[256,256] fp32.
// R19 = R17 (full-fp8 QK+PV, static per-row shift, diag-resid) with the
// out-GEMM FUSED into the attention kernel. Split-K moved inside the block
// (8 waves = 2 j-groups x 4 waves; static shift makes partials addable).
// Epilogue: l-merge (LDS) -> g1 partial O -> g0 merge (+resid, x 1/l) into
// swizzled ctx LDS -> all-wave W-GEMM (ctx from LDS, W from L2) -> out fp32.
// Eliminates: outgemm kernel, ctxP (64MB round-trip), Ld.
// grid 256 = 8b x 32qt; 512 thr; LDS 128KB + 1KB -> 1 block/CU (2 w/SIMD).
// ws: xT8[b][N][C] fp8 | xC8p[b][C][Nperm] fp8 | resid[b][N][C] bf16 |
//     Wb bf16 | Mrow float[b][N]

typedef __attribute__((ext_vector_type(8))) short short8;
typedef __attribute__((ext_vector_type(4))) float floatx4;
typedef __attribute__((ext_vector_type(16))) float floatx16;
typedef __attribute__((ext_vector_type(4))) int intx4;
typedef __attribute__((ext_vector_type(8))) int intx8;

#define N_TOK 4096
#define C_DIM 256
#define JT 64
#define NT 32  // 2048 / JT per j-group
#define SC 0.09016844005556021f  // log2(e)/16

typedef const __attribute__((address_space(1))) unsigned int g_uint;
typedef __attribute__((address_space(3))) unsigned int lds_uint;

__device__ __forceinline__ void gll16(const void* g, void* l) {
  __builtin_amdgcn_global_load_lds((g_uint*)g, (lds_uint*)l, 16, 0, 0);
}

__device__ __forceinline__ unsigned short f2bf(float f) {
  unsigned int u = __builtin_bit_cast(unsigned int, f);
  u += 0x7fffu + ((u >> 16) & 1u);
  return (unsigned short)(u >> 16);
}
__device__ __forceinline__ float bf2f(unsigned short v) {
  return __builtin_bit_cast(float, (unsigned int)v << 16);
}
// f32 -> fp8 e4m3fn, RNE, flush-subnormal, clamp 448
__device__ __forceinline__ unsigned char f2f8(float f) {
  unsigned u = __builtin_bit_cast(unsigned, f);
  unsigned sgn = (u >> 24) & 0x80u;
  unsigned a = u & 0x7fffffffu;
  if (a > 0x43e40000u) return (unsigned char)(sgn | 0x7e);
  unsigned lsb = (a >> 20) & 1u;
  a += 0x0007ffffu + lsb;
  int e = (int)(a >> 23) - 127;
  if (e < -6) return (unsigned char)sgn;
  if (e > 8) return (unsigned char)(sgn | 0x7e);
  unsigned m = (a >> 20) & 7u;
  return (unsigned char)(sgn | ((unsigned)(e + 7) << 3) | m);
}
// fp8 e4m3fn -> f32 (matches HW decode incl. subnormals)
__device__ __forceinline__ float f8dec(unsigned b) {
  unsigned s = (b & 0x80u) << 24;
  unsigned e = (b >> 3) & 15u;
  unsigned m = b & 7u;
  if (e)
    return __builtin_bit_cast(float, s | ((e + 120u) << 23) | (m << 20));
  float sub = (float)m * 0.001953125f;
  return (b & 0x80u) ? -sub : sub;
}

__device__ __forceinline__ floatx16 mfma32(short8 a, short8 b, floatx16 c) {
  return __builtin_amdgcn_mfma_f32_32x32x16_bf16(a, b, c, 0, 0, 0);
}
__device__ __forceinline__ floatx16 mfma8(intx8 a, intx8 b, floatx16 c) {
  return __builtin_amdgcn_mfma_scale_f32_32x32x64_f8f6f4(
      a, b, c, 0, 0, 0, 0x7f7f7f7f, 0, 0x7f7f7f7f);
}
template <bool HI>
__device__ __forceinline__ int pk_fp8(float a, float b, int old) {
#if __has_builtin(__builtin_amdgcn_cvt_pk_fp8_f32)
  return __builtin_amdgcn_cvt_pk_fp8_f32(a, b, old, HI);
#else
  unsigned w = (unsigned)f2f8(a) | ((unsigned)f2f8(b) << 8);
  return HI ? (int)(((unsigned)old & 0x0000ffffu) | (w << 16))
            : (int)(((unsigned)old & 0xffff0000u) | w);
#endif
}

// ctx LDS layout: elem (I, c) at I*512 + (((c>>3) ^ (I&31))<<4) + (c&7)*2
__device__ __forceinline__ int ctx_byte(int I, int c) {
  return I * 512 + ((((c >> 3) ^ (I & 31))) << 4) + (c & 7) * 2;
}

// perm: kappa(j) = ((j>>2)&1)*32 + ((j>>5)&1)*16 + ((j>>3)&3)*4 + (j&3)

// ---- K1a: x -> xT8[i][c] fp8, resid[i][c] bf16, xC8p[c][j-perm] fp8 ----
__global__ __launch_bounds__(256) void transpose_conv(
    const float* __restrict__ x, unsigned char* __restrict__ xT8,
    unsigned char* __restrict__ xC8p, unsigned short* __restrict__ resid) {
  __shared__ float tile[32][33];
  const int b = blockIdx.z;
  const int i0 = blockIdx.x * 32, c0 = blockIdx.y * 32;
  const int tx = threadIdx.x & 31, ty = threadIdx.x >> 5;
  const float* xb = x + (size_t)b * C_DIM * N_TOK;
#pragma unroll
  for (int p = 0; p < 4; ++p) {
    int c = c0 + ty + p * 8;
    float v = xb[(size_t)c * N_TOK + i0 + tx];
    tile[ty + p * 8][tx] = v;
    int j = i0 + tx, jg = j & 63;
    int kp = ((jg >> 2) & 1) * 32 + ((jg >> 5) & 1) * 16 + ((jg >> 3) & 3) * 4 + (jg & 3);
    xC8p[((size_t)b * C_DIM + c) * N_TOK + (j & ~63) + kp] = f2f8(v);
  }
  __syncthreads();
#pragma unroll
  for (int p = 0; p < 4; ++p) {
    int i = i0 + ty + p * 8;
    float v = tile[tx][ty + p * 8];
    unsigned char q8 = f2f8(v);
    size_t idx = ((size_t)b * N_TOK + i) * C_DIM + c0 + tx;
    xT8[idx] = q8;
    resid[idx] = f2bf(v - f8dec(q8));
  }
}

// ---- K1b: W fp32 -> bf16 ----
__global__ __launch_bounds__(256) void wconv(const float* __restrict__ W,
                                             unsigned short* __restrict__ Wb) {
  int idx = blockIdx.x * 256 + threadIdx.x;
  Wb[idx] = f2bf(W[idx]);
}

// ---- K1c: Mrow[row] = SC * sum_c dec(xT8[row][c])^2 ----
__global__ __launch_bounds__(256) void mrow_kernel(
    const unsigned char* __restrict__ xT8, float* __restrict__ Mrow) {
  const int row = blockIdx.x * 4 + (threadIdx.x >> 6);
  const int lane = threadIdx.x & 63;
  const unsigned char* rp = xT8 + (size_t)row * C_DIM + lane * 4;
  float s = 0.f;
#pragma unroll
  for (int e = 0; e < 4; ++e) {
    float v = f8dec(rp[e]);
    s += v * v;
  }
  s += __shfl_xor(s, 1);
  s += __shfl_xor(s, 2);
  s += __shfl_xor(s, 4);
  s += __shfl_xor(s, 8);
  s += __shfl_xor(s, 16);
  s += __shfl_xor(s, 32);
  if (lane == 0) Mrow[row] = s * SC;
}

// ---- K2: fused flash attention + out-GEMM. grid 256, 512 thr ----
__global__ __launch_bounds__(512, 1) void attn_kernel(
    const unsigned char* __restrict__ xT8, const unsigned char* __restrict__ xC8p,
    const float* __restrict__ Mrow, const unsigned short* __restrict__ resid,
    const unsigned short* __restrict__ Wb, float* __restrict__ out) {
  const int bid = blockIdx.x;
  const int b = bid & 7;   // batch == XCD -> L2 locality
  const int qt = bid >> 3; // q-tile (128 rows)
  const int tid = threadIdx.x;
  const int lane = tid & 63;
  const int wv = tid >> 6;   // 0..7
  const int wg = wv & 3;     // wave-in-group
  const int grp = wv >> 2;   // j-group: j in [grp*2048, grp*2048+2048)
  const int l31 = lane & 31;
  const int h = lane >> 5;
  const unsigned char* xT8b = xT8 + (size_t)b * N_TOK * C_DIM;
  const unsigned char* xCb = xC8p + (size_t)b * C_DIM * N_TOK;
  const int qb = qt * 128 + wg * 32;

  __shared__ char lds[131072];   // [grp][parity][K 16KB | V 16KB]
  __shared__ float lbuf[2][128];
  char* gbase = lds + grp * 65536;

  // staging bases (inverse-swizzled, rule #21)
  const char* kBase;
  {
    int j0 = wg * 4 + (lane >> 4);
    int c16 = (lane & 15) ^ (j0 & 15);
    kBase = (const char*)xT8b + (size_t)grp * 2048 * 256 + j0 * 256 + c16 * 16;
  }
  const char* vBase;
  {
    int c0 = wg * 16 + (lane >> 2);
    int kv = (lane & 3) ^ ((lane >> 3) & 3);
    vBase = (const char*)xCb + (size_t)c0 * N_TOK + grp * 2048 + kv * 16;
  }
  auto STAGE_K = [&](int t, int sel) {
    char* Kd = gbase + sel * 32768 + wg * 1024;
    const char* src = kBase + (size_t)t * 16384;
#pragma unroll
    for (int i = 0; i < 4; ++i) gll16(src + i * 4096, Kd + i * 4096);
  };
  auto STAGE_V = [&](int t, int sel) {
    char* Vd = gbase + sel * 32768 + 16384 + wg * 1024;
    const char* src = vBase + (size_t)t * 64;
#pragma unroll
    for (int i = 0; i < 4; ++i) gll16(src + (size_t)i * 64 * N_TOK, Vd + i * 4096);
  };

  // Q fp8 B-fragments: row qb+l31, k-bytes c = ks*64 + h*32 + [0,32)
  intx8 q[4];
  {
    const unsigned char* qp = xT8b + (size_t)(qb + l31) * C_DIM + h * 32;
#pragma unroll
    for (int ks = 0; ks < 4; ++ks) {
      intx4 lo = *(const intx4*)(qp + ks * 64);
      intx4 hi = *(const intx4*)(qp + ks * 64 + 16);
      q[ks] = (intx8){lo.x, lo.y, lo.z, lo.w, hi.x, hi.y, hi.z, hi.w};
    }
  }
  const float mi = Mrow[(size_t)b * N_TOK + qb + l31];
  const int a0 = l31 * 64 + (((2 * h) ^ ((l31 >> 1) & 3)) << 4);

  floatx16 acc[8];
#pragma unroll
  for (int ct = 0; ct < 8; ++ct)
#pragma unroll
    for (int r = 0; r < 16; ++r) acc[ct][r] = 0.f;
  float lsum = 0.f;

  STAGE_K(0, 0);
  STAGE_V(0, 0);

  for (int t = 0; t < NT; ++t) {
    __syncthreads();  // tile t staged (vmcnt drain); prev-buf reads done
    if (t + 1 < NT) {
      STAGE_K(t + 1, (t + 1) & 1);
      STAGE_V(t + 1, (t + 1) & 1);
    }
    const char* Kb = gbase + (t & 1) * 32768;
    const char* Vb = Kb + 16384;

    // S^T = mfma_scale(K8, Q8): s0 = j 0..31, s1 = j 32..63 (group-local)
    floatx16 s0, s1;
#pragma unroll
    for (int r = 0; r < 16; ++r) { s0[r] = 0.f; s1[r] = 0.f; }
    __builtin_amdgcn_s_setprio(1);
#pragma unroll
    for (int ks = 0; ks < 4; ++ks) {
      int ch = ((ks * 4 + h * 2) ^ (l31 & 15)) << 4;
      intx4 ka = *(const intx4*)(Kb + l31 * 256 + ch);
      intx4 kb2 = *(const intx4*)(Kb + l31 * 256 + (ch ^ 16));
      intx8 kf = (intx8){ka.x, ka.y, ka.z, ka.w, kb2.x, kb2.y, kb2.z, kb2.w};
      s0 = mfma8(kf, q[ks], s0);
      ka = *(const intx4*)(Kb + (32 + l31) * 256 + ch);
      kb2 = *(const intx4*)(Kb + (32 + l31) * 256 + (ch ^ 16));
      kf = (intx8){ka.x, ka.y, ka.z, ka.w, kb2.x, kb2.y, kb2.z, kb2.w};
      s1 = mfma8(kf, q[ks], s1);
    }
    __builtin_amdgcn_s_setprio(0);

    // static-shift softmax: pure per-lane
#pragma unroll
    for (int r = 0; r < 16; ++r) {
      s0[r] = exp2f(s0[r] * SC - mi);
      s1[r] = exp2f(s1[r] * SC - mi);
      lsum += s0[r] + s1[r];
    }

    int pk[8];
#pragma unroll
    for (int i = 0; i < 4; ++i) {
      int v = pk_fp8<false>(s0[4 * i], s0[4 * i + 1], 0);
      pk[i] = pk_fp8<true>(s0[4 * i + 2], s0[4 * i + 3], v);
      v = pk_fp8<false>(s1[4 * i], s1[4 * i + 1], 0);
      pk[4 + i] = pk_fp8<true>(s1[4 * i + 2], s1[4 * i + 3], v);
    }

    intx8 pa = (intx8){pk[0], pk[1], pk[2], pk[3], pk[4], pk[5], pk[6], pk[7]};
    __builtin_amdgcn_s_setprio(1);
#pragma unroll
    for (int ct = 0; ct < 8; ++ct) {
      const char* vp = Vb + ct * 2048;
      intx4 lo = *(const intx4*)(vp + a0);
      intx4 hi = *(const intx4*)(vp + (a0 ^ 16));
      intx8 vf = (intx8){lo.x, lo.y, lo.z, lo.w, hi.x, hi.y, hi.z, hi.w};
      acc[ct] = mfma8(pa, vf, acc[ct]);
    }
    __builtin_amdgcn_s_setprio(0);
  }

  // ---- fused epilogue ----
  lsum += __shfl_xor(lsum, 32);  // full j-sum for this group, row qb+l31
  __syncthreads();               // A: K/V buffers quiesce (all waves done)
  if (h == 0) lbuf[grp][wg * 32 + l31] = lsum;
  if (grp == 1) {  // write bf16 partial O to region1
#pragma unroll
    for (int r = 0; r < 16; ++r) {
      int I = wg * 32 + (r & 3) + 8 * (r >> 2) + 4 * h;
#pragma unroll
      for (int ct = 0; ct < 8; ++ct) {
        int c = ct * 32 + l31;
        *(unsigned short*)(lds + 65536 + ctx_byte(I, c)) = f2bf(acc[ct][r]);
      }
    }
  }
  __syncthreads();  // B: lbuf + g1 partials visible
  if (grp == 0) {   // merge: acc + partial + resid, x 1/l -> final ctx bf16
    const unsigned short* rbase = resid + ((size_t)b * N_TOK + qt * 128) * C_DIM;
#pragma unroll
    for (int r = 0; r < 16; ++r) {
      int I = wg * 32 + (r & 3) + 8 * (r >> 2) + 4 * h;
      float linv = 1.0f / (lbuf[0][I] + lbuf[1][I]);
#pragma unroll
      for (int ct = 0; ct < 8; ++ct) {
        int c = ct * 32 + l31;
        float pv = bf2f(*(const unsigned short*)(lds + 65536 + ctx_byte(I, c)));
        float rv = bf2f(rbase[(size_t)I * C_DIM + c]);
        *(unsigned short*)(lds + ctx_byte(I, c)) =
            f2bf((acc[ct][r] + pv + rv) * linv);
      }
    }
  }
  __syncthreads();  // C: final ctx ready

  // W-GEMM: out[o][i] = sum_c W[o][c] ctx[i][c]
  // A = W (m=o), B = ctx (n=i); wave: i-group wg, o-half grp.
  floatx16 oacc[4];
#pragma unroll
  for (int og = 0; og < 4; ++og)
#pragma unroll
    for (int r = 0; r < 16; ++r) oacc[og][r] = 0.f;
  const int Irow = wg * 32 + l31;
  __builtin_amdgcn_s_setprio(1);
#pragma unroll
  for (int ks = 0; ks < 16; ++ks) {
    short8 cfrag = *(const short8*)(lds + Irow * 512 +
                                    (((ks * 2 + h) ^ (Irow & 31)) << 4));
#pragma unroll
    for (int og = 0; og < 4; ++og) {
      const unsigned short* wp =
          Wb + (size_t)(grp * 128 + og * 32 + l31) * C_DIM + ks * 16 + h * 8;
      short8 wfrag = *(const short8*)wp;
      oacc[og] = mfma32(wfrag, cfrag, oacc[og]);
    }
  }
  __builtin_amdgcn_s_setprio(0);
  float* outb = out + (size_t)b * C_DIM * N_TOK;
  const int iglob = qt * 128 + wg * 32 + l31;
#pragma unroll
  for (int og = 0; og < 4; ++og) {
    int o0 = grp * 128 + og * 32;
#pragma unroll
    for (int r = 0; r < 16; ++r) {
      int o = o0 + (r & 3) + 8 * (r >> 2) + 4 * h;
      outb[(size_t)o * N_TOK + iglob] = oacc[og][r];
    }
  }
}

extern "C" void kernel_launch(void* const* d_in, const int* in_sizes, int n_in,
                              void* d_out, int out_size, void* d_ws, size_t ws_size,
                              hipStream_t stream) {
  const float* x = (const float*)d_in[0];
  const float* W = (const float*)d_in[1];
  float* out = (float*)d_out;
  char* ws = (char*)d_ws;
  const size_t SZ8 = (size_t)8 * N_TOK * C_DIM;  // 8 MB fp8 tensor
  unsigned char* xT8 = (unsigned char*)(ws);                    // 8 MB
  unsigned char* xC8p = (unsigned char*)(ws + SZ8);             // 8 MB
  unsigned short* resid = (unsigned short*)(ws + 2 * SZ8);      // 16 MB
  unsigned short* Wb = (unsigned short*)(ws + 4 * SZ8);         // 128 KB
  float* Mrow = (float*)(ws + 4 * SZ8 + C_DIM * C_DIM * 2);     // 128 KB

  hipLaunchKernelGGL(transpose_conv, dim3(N_TOK / 32, C_DIM / 32, 8), dim3(256), 0,
                     stream, x, xT8, xC8p, resid);
  hipLaunchKernelGGL(wconv, dim3((C_DIM * C_DIM) / 256), dim3(256), 0, stream, W, Wb);
  hipLaunchKernelGGL(mrow_kernel, dim3(8 * N_TOK / 4), dim3(256), 0, stream, xT8, Mrow);
  hipLaunchKernelGGL(attn_kernel, dim3(256), dim3(512), 0, stream, xT8, xC8p, Mrow,
                     resid, Wb, out);
}